// Round 10
// baseline (507.470 us; speedup 1.0000x reference)
//
#include <hip/hip_runtime.h>
#include <stdint.h>

#define T_LEN 8192
#define DIN   1024
#define HD    1024
#define TH    3072
#define NB    16       // buckets: 0..14 exact local_step, 15 = clamp (handled by tail_pll)
#define SKINNY_MAX 160 // pass_gemm (k<=4): S <= this -> skinny path
#define KSPLIT 5       // k >= KSPLIT handled by the merged skinny_all kernel

typedef __attribute__((ext_vector_type(8))) short bf16x8;
typedef __attribute__((ext_vector_type(4))) float f32x4;

__device__ __forceinline__ unsigned short f2bf(float x) {
    union { float f; unsigned u; } v; v.f = x;
    unsigned r = v.u + 0x7FFFu + ((v.u >> 16) & 1u);
    return (unsigned short)(r >> 16);
}

__device__ __forceinline__ float bf2f(unsigned short x) {
    union { unsigned u; float f; } v; v.u = ((unsigned)x) << 16;
    return v.f;
}

// async global->LDS, 16B per lane. LDS dest must be wave-uniform base + lane*16;
// global address may be per-lane arbitrary (gather OK).
__device__ __forceinline__ void gld16(const void* g, void* l) {
    __builtin_amdgcn_global_load_lds(
        (const __attribute__((address_space(1))) unsigned int*)(uintptr_t)g,
        (__attribute__((address_space(3))) unsigned int*)(uintptr_t)l,
        16, 0, 0);
}

__device__ __forceinline__ float sigm(float x) { return 1.f / (1.f + __expf(-x)); }
__device__ __forceinline__ float tanh_fast(float x) { return 1.f - 2.f / (1.f + __expf(2.f * x)); }

// ---------------- cast X -> bf16 ----------------
__global__ void cast_x(const float* __restrict__ X, unsigned short* __restrict__ Xb) {
    int idx = (blockIdx.x * 256 + threadIdx.x) * 4;
    float4 v = *(const float4*)(X + idx);
    ushort4 o; o.x = f2bf(v.x); o.y = f2bf(v.y); o.z = f2bf(v.z); o.w = f2bf(v.w);
    *(ushort4*)(Xb + idx) = o;
}

// ---------------- transpose+cast Wi/Wh [K][3072] -> [3072][K] bf16 ----------------
__global__ void transpose_cast(const float* __restrict__ Wi, const float* __restrict__ Wh,
                               unsigned short* __restrict__ WiT, unsigned short* __restrict__ WhT) {
    const float* src = blockIdx.z ? Wh : Wi;
    unsigned short* dst = blockIdx.z ? WhT : WiT;
    int n0 = blockIdx.x * 64, k0 = blockIdx.y * 64;
    __shared__ unsigned short tile[64][65];
    int tid = threadIdx.x;
    for (int p = 0; p < 16; p++) {
        int idx = tid + p * 256;
        int kl = idx >> 6, nl = idx & 63;
        tile[kl][nl] = f2bf(src[(size_t)(k0 + kl) * TH + n0 + nl]);
    }
    __syncthreads();
    for (int p = 0; p < 16; p++) {
        int idx = tid + p * 256;
        int nl = idx >> 6, kl = idx & 63;
        dst[(size_t)(n0 + nl) * 1024 + k0 + kl] = tile[kl][nl];
    }
}

// ---------------- segment metadata (1 block, 1024 threads) ----------------
// meta[0..NB): counts ; meta[NB..2NB): offsets ; meta[2NB]: last_state flag ;
// meta[48]: tail_pll barrier counter ; meta[49]: skinny_all barrier counter
__global__ void meta_kernel(const int* __restrict__ term, const float* __restrict__ last_state,
                            int* __restrict__ pos_list, int* __restrict__ meta) {
    __shared__ int part[1024];
    __shared__ int cnt[NB];
    __shared__ int cur[NB];
    __shared__ int flag;
    int tid = threadIdx.x;
    if (tid < NB) cnt[tid] = 0;
    if (tid == 0) flag = 0;
    __syncthreads();
    int base = tid * 8;
    int mx = -1;
    for (int u = 0; u < 8; u++) {
        int t = base + u;
        int s = (t == 0 || term[t] != 0) ? t : -1;
        mx = s > mx ? s : mx;
    }
    part[tid] = mx;
    __syncthreads();
    for (int d = 1; d < 1024; d <<= 1) {
        int a = part[tid];
        int b = (tid >= d) ? part[tid - d] : -1;
        __syncthreads();
        part[tid] = a > b ? a : b;
        __syncthreads();
    }
    int run = (tid > 0) ? part[tid - 1] : -1;
    int kk[8];
    for (int u = 0; u < 8; u++) {
        int t = base + u;
        int s = (t == 0 || term[t] != 0) ? t : -1;
        run = s > run ? s : run;
        int ls = t - run;
        int k = ls < NB ? ls : NB - 1;
        kk[u] = k;
        atomicAdd(&cnt[k], 1);
    }
    if (last_state[tid] != 0.0f) atomicOr(&flag, 1);
    __syncthreads();
    if (tid == 0) {
        int off = 0;
        for (int k = 0; k < NB; k++) {
            meta[k] = cnt[k];
            meta[NB + k] = off;
            cur[k] = off;
            off += cnt[k];
        }
        meta[2 * NB] = flag;
        meta[48] = 0;                 // tail_pll barrier counter
        meta[49] = 0;                 // skinny_all barrier counter
    }
    __syncthreads();
    for (int u = 0; u < 8; u++) {
        int idx = atomicAdd(&cur[kk[u]], 1);
        pos_list[idx] = base + u;
    }
}

// ---------------- gi = Xb @ WiT^T + bi  (verified BK=32 form + XCD-aware swizzle) ----
// r7: BK=64 regressed (bank conflicts 3x, occupancy -10pt) — BK=32 is the optimum for
// this structure; do NOT raise BK. New this round: bijective XCD swizzle (1536 blocks,
// 1536%8==0) so each XCD owns 8 consecutive m-panels -> 8x A-panel L2 locality.
__global__ __launch_bounds__(256) void gemm_gi(const unsigned short* __restrict__ Xb,
                                               const unsigned short* __restrict__ WiT,
                                               const float* __restrict__ bi,
                                               float* __restrict__ gi) {
    __shared__ unsigned short As[128 * 32];
    __shared__ unsigned short Bs[128 * 32];
    int tid = threadIdx.x;
    int phys = blockIdx.y * gridDim.x + blockIdx.x;       // 0..1535, XCD = phys & 7
    int logi = (phys & 7) * 192 + (phys >> 3);            // bijective (1536/8 = 192)
    int m0 = (logi / 24) * 128, n0 = (logi % 24) * 128;
    int lane = tid & 63, wave = tid >> 6;
    int wm = wave & 1, wn = wave >> 1;
    int quad = lane >> 4, l16 = lane & 15;
    f32x4 acc[4][4] = {};   // 16 f32x4 = promotion ceiling; do NOT enlarge (r2: 24 -> scratch spill)
    for (int kb = 0; kb < 32; kb++) {
        int k0 = kb * 32;
        for (int p = 0; p < 2; p++) {
            int c = tid + p * 256;
            int row = c >> 2, cb = c & 3;
            gld16(Xb + (size_t)(m0 + row) * 1024 + k0 + cb * 8, As + c * 8);
            gld16(WiT + (size_t)(n0 + row) * 1024 + k0 + cb * 8, Bs + c * 8);
        }
        __syncthreads();
        bf16x8 af[4], bfr[4];
        for (int i = 0; i < 4; i++)
            af[i] = *(const bf16x8*)(As + (wm * 64 + i * 16 + l16) * 32 + quad * 8);
        for (int j = 0; j < 4; j++)
            bfr[j] = *(const bf16x8*)(Bs + (wn * 64 + j * 16 + l16) * 32 + quad * 8);
        for (int i = 0; i < 4; i++)
            for (int j = 0; j < 4; j++)
                acc[i][j] = __builtin_amdgcn_mfma_f32_16x16x32_bf16(af[i], bfr[j], acc[i][j], 0, 0, 0);
        __syncthreads();
    }
    for (int j = 0; j < 4; j++) {
        int col = n0 + wn * 64 + j * 16 + l16;
        float bv = bi[col];
        for (int i = 0; i < 4; i++) {
            int rbase = m0 + wm * 64 + i * 16 + quad * 4;
            for (int r = 0; r < 4; r++)
                gi[(size_t)(rbase + r) * TH + col] = acc[i][j][r] + bv;
        }
    }
}

// ---------------- pass 0: segment starts, h_prev == 0 (or last_state for t==0) ----------
__global__ void pass0_kernel(const float* __restrict__ gi, const float* __restrict__ bhn,
                             const float* __restrict__ last_state, const float* __restrict__ Wh,
                             const int* __restrict__ term, const int* __restrict__ pos_list,
                             const int* __restrict__ meta, float* __restrict__ out,
                             unsigned short* __restrict__ hb) {
    int S0 = meta[0];
    int b = blockIdx.x;
    if (b >= S0) return;
    int t = pos_list[meta[NB] + b];
    int tid = threadIdx.x;
    bool ls_path = (t == 0) && (term[0] == 0) && (meta[2 * NB] != 0);
    for (int u = 0; u < 4; u++) {
        int j = tid + u * 256;
        float gr = gi[(size_t)t * TH + j];
        float gz = gi[(size_t)t * TH + 1024 + j];
        float gn = gi[(size_t)t * TH + 2048 + j];
        float hp = 0.f, ghr = 0.f, ghz = 0.f, ghn = 0.f;
        if (ls_path) {  // general fallback (last_state != 0); not taken for this dataset
            hp = last_state[j];
            for (int k = 0; k < 1024; k++) {
                float hk = last_state[k];
                const float* w = Wh + (size_t)k * TH;
                ghr += hk * w[j]; ghz += hk * w[1024 + j]; ghn += hk * w[2048 + j];
            }
        }
        float r = sigm(gr + ghr);
        float z = sigm(gz + ghz);
        float n = tanh_fast(gn + r * (ghn + bhn[j]));
        float h = (1.f - z) * n + z * hp;
        out[(size_t)t * HD + j] = h;
        out[(size_t)(T_LEN + t) * HD + j] = h;
        hb[(size_t)t * HD + j] = f2bf(h);
    }
}

// ---------------- pass k in [1,4]: gathered-row GEMM h_prev @ Wh + fused gates --------
// Two paths selected at runtime on S = meta[k] (uniform across grid):
//  - S >  SKINNY_MAX: LDS path (verified round-0 form).
//  - S <= SKINNY_MAX: skinny barrier-free direct-L2 wave-tile path (verified round-2).
__global__ __launch_bounds__(256) void pass_gemm(const float* __restrict__ gi,
                                                 const float* __restrict__ bhn,
                                                 const unsigned short* __restrict__ WhT,
                                                 const unsigned short* __restrict__ hb,
                                                 float* __restrict__ out,
                                                 unsigned short* __restrict__ hbw,
                                                 const int* __restrict__ pos_list,
                                                 const int* __restrict__ meta, int k) {
    int S = meta[k];
    int off = meta[NB + k];
    int tid = threadIdx.x;
    int lane = tid & 63, wave = tid >> 6;
    int quad = lane >> 4, l16 = lane & 15;

    if (S <= SKINNY_MAX) {
        if (S == 0) return;
        int nrt = (S + 15) >> 4;
        int ntask = 64 * nrt;                       // 64 h-col tiles x row tiles
        int gwave = ((blockIdx.y * 16 + blockIdx.x) << 2) + wave;
        int nw = gridDim.x * gridDim.y * 4;
        for (int task = gwave; task < ntask; task += nw) {
            int ct = task & 63;
            int rt = task >> 6;
            int j = ct * 16 + l16;                  // h-col this lane owns
            int ra = rt * 16 + l16;
            ra = ra < S ? ra : S - 1;               // clamp: dup loads harmless
            int t_a = pos_list[off + ra];
            const unsigned short* ap = hb + (size_t)(t_a - 1) * HD + quad * 8;
            const unsigned short* bp = WhT + (size_t)j * 1024 + quad * 8;
            f32x4 acc[3] = {};
            #pragma unroll
            for (int ks = 0; ks < 32; ks++) {
                bf16x8 a  = *(const bf16x8*)(ap + ks * 32);
                bf16x8 b0 = *(const bf16x8*)(bp + ks * 32);
                bf16x8 b1 = *(const bf16x8*)(bp + 1048576 + ks * 32);   // gate z row block
                bf16x8 b2 = *(const bf16x8*)(bp + 2097152 + ks * 32);   // gate n row block
                acc[0] = __builtin_amdgcn_mfma_f32_16x16x32_bf16(a, b0, acc[0], 0, 0, 0);
                acc[1] = __builtin_amdgcn_mfma_f32_16x16x32_bf16(a, b1, acc[1], 0, 0, 0);
                acc[2] = __builtin_amdgcn_mfma_f32_16x16x32_bf16(a, b2, acc[2], 0, 0, 0);
            }
            // C layout: col = l16 (h-col j), row = quad*4 + r (row within 16-row tile)
            #pragma unroll
            for (int r = 0; r < 4; r++) {
                int rr = rt * 16 + quad * 4 + r;
                if (rr >= S) continue;
                int t = pos_list[off + rr];
                const float* girow = gi + (size_t)t * TH;
                float hp = out[(size_t)(t - 1) * HD + j];
                float rgt = sigm(girow[j] + acc[0][r]);
                float zgt = sigm(girow[1024 + j] + acc[1][r]);
                float ngt = tanh_fast(girow[2048 + j] + rgt * (acc[2][r] + bhn[j]));
                float hv = (1.f - zgt) * ngt + zgt * hp;
                out[(size_t)t * HD + j] = hv;
                out[(size_t)(T_LEN + t) * HD + j] = hv;
                hbw[(size_t)t * HD + j] = f2bf(hv);
            }
        }
        return;
    }

    // ---------------- LDS path (verified round-0 form) ----------------
    int r0 = blockIdx.y * 64;
    if (r0 >= S) return;
    int j0 = blockIdx.x * 64;
    __shared__ unsigned short As[4 * 64 * 32];    // 16 KB (four 32-K sub-tiles)
    __shared__ unsigned short Bs[4 * 192 * 32];   // 48 KB (row: gate g*64 + jj)
    int wm = wave & 1, wn = wave >> 1;

    // A gather: 256 chunks per sub-tile; chunk id = tid; row=tid>>2, sub=tid&3.
    int arow = tid >> 2, sub = tid & 3;
    bool av = (r0 + arow) < S;
    int t_a = av ? pos_list[off + r0 + arow] : 1;
    const unsigned short* hsrc = hb + (size_t)(t_a - 1) * HD + sub * 8;

    f32x4 acc[2][6] = {};
    for (int kb = 0; kb < 8; kb++) {
        int k0 = kb * 128;
        for (int ks = 0; ks < 4; ks++) {
            int kk0 = k0 + ks * 32;
            for (int p = 0; p < 3; p++) {      // B sub-tile: 768 chunks
                int c = tid + p * 256;
                int row = c >> 2, q = c & 3;
                int g = row >> 6, jj = row & 63;
                gld16(WhT + (size_t)(g * 1024 + j0 + jj) * 1024 + kk0 + q * 8,
                      Bs + ks * 6144 + c * 8);
            }
            // A sub-tile: 256 chunks (gathered rows; garbage rows >= S harmless)
            gld16(hsrc + kk0, As + ks * 2048 + tid * 8);
        }
        __syncthreads();
        for (int ks = 0; ks < 4; ks++) {
            bf16x8 af[2];
            for (int i = 0; i < 2; i++)
                af[i] = *(const bf16x8*)(As + ks * 2048 + (wm * 32 + i * 16 + l16) * 32 + quad * 8);
            for (int n = 0; n < 6; n++) {
                int g = n >> 1, jh = n & 1;
                bf16x8 bv = *(const bf16x8*)(Bs + ks * 6144 + (g * 64 + wn * 32 + jh * 16 + l16) * 32 + quad * 8);
                for (int i = 0; i < 2; i++)
                    acc[i][n] = __builtin_amdgcn_mfma_f32_16x16x32_bf16(af[i], bv, acc[i][n], 0, 0, 0);
            }
        }
        __syncthreads();
    }
    // epilogue: rows r0 + wm*32 + i*16 + quad*4 + r ; cols j0 + wn*32 + jh*16 + l16
    for (int i = 0; i < 2; i++) {
        for (int r = 0; r < 4; r++) {
            int rr = r0 + wm * 32 + i * 16 + quad * 4 + r;
            if (rr >= S) continue;
            int t = pos_list[off + rr];
            const float* girow = gi + (size_t)t * TH;
            const float* hprow = out + (size_t)(t - 1) * HD;
            float* o1 = out + (size_t)t * HD;
            float* o2 = out + (size_t)(T_LEN + t) * HD;
            unsigned short* hbrow = hbw + (size_t)t * HD;
            for (int jh = 0; jh < 2; jh++) {
                int j = j0 + wn * 32 + jh * 16 + l16;
                float ghr = acc[i][0 + jh][r];
                float ghz = acc[i][2 + jh][r];
                float ghn = acc[i][4 + jh][r];
                float rg = sigm(girow[j] + ghr);
                float zg = sigm(girow[1024 + j] + ghz);
                float ng = tanh_fast(girow[2048 + j] + rg * (ghn + bhn[j]));
                float h = (1.f - zg) * ng + zg * hprow[j];
                o1[j] = h;
                o2[j] = h;
                hbrow[j] = f2bf(h);
            }
        }
    }
}

// ---------------- merged skinny passes k=KSPLIT..14 — ONE launch, manual barriers ----
// r9 post-mortem: ~230us of the 431 total is unaccounted by dispatch models; prime
// suspect is per-launch serialization gaps (~18 launches). This kernel replaces 10
// launches with 1. 128 blocks x 256 thr (trivially co-resident, launched alone
// in-stream) run the verified skinny task loop per level; between levels a manual
// device-scope barrier (release fence -> atomic arrive -> spin -> acquire fence).
// NOT coop grid.sync (r1: 86us/sync at 256-block scale). Bucket monotonicity
// (S_k==0 => S_{k+1}==0 and S_15==0) makes the early break uniform and safe.
// Correct for ANY S (task loop); skips the barrier after the last nonempty level.
__global__ __launch_bounds__(256) void skinny_all(const float* __restrict__ gi,
                                                  const float* __restrict__ bhn,
                                                  const unsigned short* __restrict__ WhT,
                                                  unsigned short* __restrict__ hb,
                                                  float* __restrict__ out,
                                                  const int* __restrict__ pos_list,
                                                  const int* __restrict__ meta,
                                                  int* __restrict__ syncc) {
    int tid = threadIdx.x;
    int lane = tid & 63, wave = tid >> 6;
    int quad = lane >> 4, l16 = lane & 15;
    int gwave = (blockIdx.x << 2) + wave;     // 0..511
    int gen = 0;
    for (int k = KSPLIT; k <= NB - 2; k++) {
        int S = meta[k];
        if (S == 0) break;                    // uniform: later buckets (and tail) empty
        int off = meta[NB + k];
        int nrt = (S + 15) >> 4;
        int ntask = 64 * nrt;
        for (int task = gwave; task < ntask; task += 512) {
            int ct = task & 63;
            int rt = task >> 6;
            int j = ct * 16 + l16;
            int ra = rt * 16 + l16;
            ra = ra < S ? ra : S - 1;
            int t_a = pos_list[off + ra];
            const unsigned short* ap = hb + (size_t)(t_a - 1) * HD + quad * 8;
            const unsigned short* bp = WhT + (size_t)j * 1024 + quad * 8;
            f32x4 acc[3] = {};
            #pragma unroll
            for (int ks = 0; ks < 32; ks++) {
                bf16x8 a  = *(const bf16x8*)(ap + ks * 32);
                bf16x8 b0 = *(const bf16x8*)(bp + ks * 32);
                bf16x8 b1 = *(const bf16x8*)(bp + 1048576 + ks * 32);
                bf16x8 b2 = *(const bf16x8*)(bp + 2097152 + ks * 32);
                acc[0] = __builtin_amdgcn_mfma_f32_16x16x32_bf16(a, b0, acc[0], 0, 0, 0);
                acc[1] = __builtin_amdgcn_mfma_f32_16x16x32_bf16(a, b1, acc[1], 0, 0, 0);
                acc[2] = __builtin_amdgcn_mfma_f32_16x16x32_bf16(a, b2, acc[2], 0, 0, 0);
            }
            #pragma unroll
            for (int r = 0; r < 4; r++) {
                int rr = rt * 16 + quad * 4 + r;
                if (rr >= S) continue;
                int t = pos_list[off + rr];
                const float* girow = gi + (size_t)t * TH;
                float hp = out[(size_t)(t - 1) * HD + j];
                float rgt = sigm(girow[j] + acc[0][r]);
                float zgt = sigm(girow[1024 + j] + acc[1][r]);
                float ngt = tanh_fast(girow[2048 + j] + rgt * (acc[2][r] + bhn[j]));
                float hv = (1.f - zgt) * ngt + zgt * hp;
                out[(size_t)t * HD + j] = hv;
                out[(size_t)(T_LEN + t) * HD + j] = hv;
                hb[(size_t)t * HD + j] = f2bf(hv);
            }
        }
        // skip barrier if nothing follows (uniform decision)
        if (k == NB - 2 || meta[k + 1] == 0) break;
        gen++;
        __syncthreads();
        __threadfence();                       // release: publish level-k writes
        if (tid == 0) {
            atomicAdd(syncc, 1);               // arrive
            while (atomicAdd(syncc, 0) < 128 * gen)
                __builtin_amdgcn_s_sleep(4);
        }
        __syncthreads();
        __threadfence();                       // acquire: see other XCDs' writes
    }
}

// ---------------- tail: positions with local_step >= NB-1 (expected S==0) ----------
__global__ __launch_bounds__(256) void tail_pll(const float* __restrict__ gi,
                                                const float* __restrict__ bhn,
                                                const unsigned short* __restrict__ WhT,
                                                const int* __restrict__ pos_list,
                                                const int* __restrict__ meta,
                                                int* __restrict__ sync,
                                                float* __restrict__ out) {
    int S = meta[NB - 1];
    if (S == 0) return;
    __shared__ int pos[T_LEN];        // 32 KB: correctness path for any S
    __shared__ float hsh[HD];
    __shared__ float dots[192];
    int off = meta[NB + NB - 1];
    int tid = threadIdx.x;
    int j0 = blockIdx.x * 64;
    for (int i = tid; i < S; i += 256) pos[i] = pos_list[off + i];
    __syncthreads();
    if (tid == 0) {   // insertion sort by t (S expected tiny; redundant per block)
        for (int i = 1; i < S; i++) {
            int v = pos[i], j = i - 1;
            while (j >= 0 && pos[j] > v) { pos[j + 1] = pos[j]; j--; }
            pos[j + 1] = v;
        }
    }
    __syncthreads();
    for (int s = 0; s < S; s++) {
        int t = pos[s];
        for (int u = 0; u < 4; u++)    // stage h_prev (f32, from out)
            hsh[tid + u * 256] = out[(size_t)(t - 1) * HD + tid + u * 256];
        __syncthreads();
        if (tid < 192) {
            int g = tid >> 6, jj = tid & 63;
            int col = g * 1024 + j0 + jj;
            const unsigned short* wrow = WhT + (size_t)col * 1024;
            float acc = 0.f;
            for (int kk = 0; kk < 1024; kk += 8) {
                bf16x8 wv = *(const bf16x8*)(wrow + kk);
                f32x4 h0 = *(const f32x4*)(hsh + kk);
                f32x4 h1 = *(const f32x4*)(hsh + kk + 4);
                acc += h0[0] * bf2f((unsigned short)wv[0]) + h0[1] * bf2f((unsigned short)wv[1])
                     + h0[2] * bf2f((unsigned short)wv[2]) + h0[3] * bf2f((unsigned short)wv[3])
                     + h1[0] * bf2f((unsigned short)wv[4]) + h1[1] * bf2f((unsigned short)wv[5])
                     + h1[2] * bf2f((unsigned short)wv[6]) + h1[3] * bf2f((unsigned short)wv[7]);
            }
            dots[tid] = acc;
        }
        __syncthreads();
        if (tid < 64) {
            int j = j0 + tid;
            float rg = sigm(gi[(size_t)t * TH + j] + dots[tid]);
            float zg = sigm(gi[(size_t)t * TH + 1024 + j] + dots[64 + tid]);
            float ng = tanh_fast(gi[(size_t)t * TH + 2048 + j] + rg * (dots[128 + tid] + bhn[j]));
            float hv = (1.f - zg) * ng + zg * hsh[j];
            out[(size_t)t * HD + j] = hv;
            out[(size_t)(T_LEN + t) * HD + j] = hv;
        }
        // ---- manual device-scope inter-block barrier ----
        __threadfence();
        __syncthreads();
        if (tid == 0) {
            atomicAdd(sync, 1);
            int tgt = 16 * (s + 1);
            while (atomicAdd(sync, 0) < tgt)
                __builtin_amdgcn_s_sleep(8);
        }
        __syncthreads();
        __threadfence();
    }
}

extern "C" void kernel_launch(void* const* d_in, const int* in_sizes, int n_in,
                              void* d_out, int out_size, void* d_ws, size_t ws_size,
                              hipStream_t stream) {
    const float* X          = (const float*)d_in[0];
    const int*   term       = (const int*)d_in[1];
    const float* last_state = (const float*)d_in[2];
    const float* Wi         = (const float*)d_in[3];
    const float* bi         = (const float*)d_in[4];
    const float* Wh         = (const float*)d_in[5];
    const float* bhn        = (const float*)d_in[6];
    float* out = (float*)d_out;

    char* ws = (char*)d_ws;
    float*          gi       = (float*)ws;                         // 100,663,296 B
    unsigned short* Xb       = (unsigned short*)(ws + 100663296);  // 16,777,216 B (reused as hb)
    unsigned short* hb       = Xb;  // Xb dead after gemm_gi; stream order guarantees safety
    unsigned short* WiT      = (unsigned short*)(ws + 117440512);  //  6,291,456 B
    unsigned short* WhT      = (unsigned short*)(ws + 123731968);  //  6,291,456 B
    int*            pos_list = (int*)(ws + 130023424);             //     32,768 B
    int*            meta     = (int*)(ws + 130056192);             //        512 B
    int*            sync_t   = meta + 48;                          // tail barrier counter
    int*            sync_s   = meta + 49;                          // skinny barrier counter

    cast_x<<<dim3(8192), dim3(256), 0, stream>>>(X, Xb);
    transpose_cast<<<dim3(48, 16, 2), dim3(256), 0, stream>>>(Wi, Wh, WiT, WhT);
    meta_kernel<<<dim3(1), dim3(1024), 0, stream>>>(term, last_state, pos_list, meta);
    gemm_gi<<<dim3(24, 64), dim3(256), 0, stream>>>(Xb, WiT, bi, gi);
    pass0_kernel<<<dim3(8192), dim3(256), 0, stream>>>(gi, bhn, last_state, Wh, term, pos_list, meta, out, hb);
    for (int k = 1; k < KSPLIT; k++) {
        int rows_max = T_LEN / (k + 1);     // S_k <= T/(k+1)
        int gy = (rows_max + 63) / 64;
        pass_gemm<<<dim3(16, gy), dim3(256), 0, stream>>>(gi, bhn, WhT, hb, out, hb, pos_list, meta, k);
    }
    skinny_all<<<dim3(128), dim3(256), 0, stream>>>(gi, bhn, WhT, hb, out, pos_list, meta, sync_s);
    tail_pll<<<dim3(16), dim3(256), 0, stream>>>(gi, bhn, WhT, pos_list, meta, sync_t, out);
}

// Round 11
// 457.150 us; speedup vs baseline: 1.1101x; 1.1101x over previous
//
#include <hip/hip_runtime.h>
#include <stdint.h>

#define T_LEN 8192
#define DIN   1024
#define HD    1024
#define TH    3072
#define NB    16       // buckets: 0..14 exact local_step, 15 = clamp (handled by tail_pll)
#define SKINNY_MAX 160 // pass_gemm (k<=4): S <= this -> skinny path
#define KSPLIT 5       // k >= KSPLIT handled by the merged skinny_all kernel

typedef __attribute__((ext_vector_type(8))) short bf16x8;
typedef __attribute__((ext_vector_type(4))) float f32x4;

__device__ __forceinline__ unsigned short f2bf(float x) {
    union { float f; unsigned u; } v; v.f = x;
    unsigned r = v.u + 0x7FFFu + ((v.u >> 16) & 1u);
    return (unsigned short)(r >> 16);
}

__device__ __forceinline__ float bf2f(unsigned short x) {
    union { unsigned u; float f; } v; v.u = ((unsigned)x) << 16;
    return v.f;
}

// async global->LDS, 16B per lane. LDS dest must be wave-uniform base + lane*16;
// global address may be per-lane arbitrary (gather OK).
__device__ __forceinline__ void gld16(const void* g, void* l) {
    __builtin_amdgcn_global_load_lds(
        (const __attribute__((address_space(1))) unsigned int*)(uintptr_t)g,
        (__attribute__((address_space(3))) unsigned int*)(uintptr_t)l,
        16, 0, 0);
}

__device__ __forceinline__ float sigm(float x) { return 1.f / (1.f + __expf(-x)); }
__device__ __forceinline__ float tanh_fast(float x) { return 1.f - 2.f / (1.f + __expf(2.f * x)); }

// ---------------- cast X -> bf16 ----------------
__global__ void cast_x(const float* __restrict__ X, unsigned short* __restrict__ Xb) {
    int idx = (blockIdx.x * 256 + threadIdx.x) * 4;
    float4 v = *(const float4*)(X + idx);
    ushort4 o; o.x = f2bf(v.x); o.y = f2bf(v.y); o.z = f2bf(v.z); o.w = f2bf(v.w);
    *(ushort4*)(Xb + idx) = o;
}

// ---------------- transpose+cast Wi/Wh [K][3072] -> [3072][K] bf16 ----------------
__global__ void transpose_cast(const float* __restrict__ Wi, const float* __restrict__ Wh,
                               unsigned short* __restrict__ WiT, unsigned short* __restrict__ WhT) {
    const float* src = blockIdx.z ? Wh : Wi;
    unsigned short* dst = blockIdx.z ? WhT : WiT;
    int n0 = blockIdx.x * 64, k0 = blockIdx.y * 64;
    __shared__ unsigned short tile[64][65];
    int tid = threadIdx.x;
    for (int p = 0; p < 16; p++) {
        int idx = tid + p * 256;
        int kl = idx >> 6, nl = idx & 63;
        tile[kl][nl] = f2bf(src[(size_t)(k0 + kl) * TH + n0 + nl]);
    }
    __syncthreads();
    for (int p = 0; p < 16; p++) {
        int idx = tid + p * 256;
        int nl = idx >> 6, kl = idx & 63;
        dst[(size_t)(n0 + nl) * 1024 + k0 + kl] = tile[kl][nl];
    }
}

// ---------------- segment metadata (1 block, 1024 threads) ----------------
// meta[0..NB): counts ; meta[NB..2NB): offsets ; meta[2NB]: last_state flag ;
// meta[48]: tail_pll barrier counter
__global__ void meta_kernel(const int* __restrict__ term, const float* __restrict__ last_state,
                            int* __restrict__ pos_list, int* __restrict__ meta) {
    __shared__ int part[1024];
    __shared__ int cnt[NB];
    __shared__ int cur[NB];
    __shared__ int flag;
    int tid = threadIdx.x;
    if (tid < NB) cnt[tid] = 0;
    if (tid == 0) flag = 0;
    __syncthreads();
    int base = tid * 8;
    int mx = -1;
    for (int u = 0; u < 8; u++) {
        int t = base + u;
        int s = (t == 0 || term[t] != 0) ? t : -1;
        mx = s > mx ? s : mx;
    }
    part[tid] = mx;
    __syncthreads();
    for (int d = 1; d < 1024; d <<= 1) {
        int a = part[tid];
        int b = (tid >= d) ? part[tid - d] : -1;
        __syncthreads();
        part[tid] = a > b ? a : b;
        __syncthreads();
    }
    int run = (tid > 0) ? part[tid - 1] : -1;
    int kk[8];
    for (int u = 0; u < 8; u++) {
        int t = base + u;
        int s = (t == 0 || term[t] != 0) ? t : -1;
        run = s > run ? s : run;
        int ls = t - run;
        int k = ls < NB ? ls : NB - 1;
        kk[u] = k;
        atomicAdd(&cnt[k], 1);
    }
    if (last_state[tid] != 0.0f) atomicOr(&flag, 1);
    __syncthreads();
    if (tid == 0) {
        int off = 0;
        for (int k = 0; k < NB; k++) {
            meta[k] = cnt[k];
            meta[NB + k] = off;
            cur[k] = off;
            off += cnt[k];
        }
        meta[2 * NB] = flag;
        meta[48] = 0;                 // tail_pll barrier counter
    }
    __syncthreads();
    for (int u = 0; u < 8; u++) {
        int idx = atomicAdd(&cur[kk[u]], 1);
        pos_list[idx] = base + u;
    }
}

// ---------------- gi = Xb @ WiT^T + bi  (verified BK=32 form, r9: 82us) ----
// r7: BK=64 regressed (bank conflicts 3x, occupancy -10pt) — do NOT raise BK.
// r10: XCD swizzle effect unverifiable (masked) and working set is L3-fit where
// swizzle can cost ~2% — reverted to the plain verified mapping.
__global__ __launch_bounds__(256) void gemm_gi(const unsigned short* __restrict__ Xb,
                                               const unsigned short* __restrict__ WiT,
                                               const float* __restrict__ bi,
                                               float* __restrict__ gi) {
    __shared__ unsigned short As[128 * 32];
    __shared__ unsigned short Bs[128 * 32];
    int tid = threadIdx.x;
    int m0 = blockIdx.y * 128, n0 = blockIdx.x * 128;
    int lane = tid & 63, wave = tid >> 6;
    int wm = wave & 1, wn = wave >> 1;
    int quad = lane >> 4, l16 = lane & 15;
    f32x4 acc[4][4] = {};   // 16 f32x4 = promotion ceiling; do NOT enlarge (r2: 24 -> scratch spill)
    for (int kb = 0; kb < 32; kb++) {
        int k0 = kb * 32;
        for (int p = 0; p < 2; p++) {
            int c = tid + p * 256;
            int row = c >> 2, cb = c & 3;
            gld16(Xb + (size_t)(m0 + row) * 1024 + k0 + cb * 8, As + c * 8);
            gld16(WiT + (size_t)(n0 + row) * 1024 + k0 + cb * 8, Bs + c * 8);
        }
        __syncthreads();
        bf16x8 af[4], bfr[4];
        for (int i = 0; i < 4; i++)
            af[i] = *(const bf16x8*)(As + (wm * 64 + i * 16 + l16) * 32 + quad * 8);
        for (int j = 0; j < 4; j++)
            bfr[j] = *(const bf16x8*)(Bs + (wn * 64 + j * 16 + l16) * 32 + quad * 8);
        for (int i = 0; i < 4; i++)
            for (int j = 0; j < 4; j++)
                acc[i][j] = __builtin_amdgcn_mfma_f32_16x16x32_bf16(af[i], bfr[j], acc[i][j], 0, 0, 0);
        __syncthreads();
    }
    for (int j = 0; j < 4; j++) {
        int col = n0 + wn * 64 + j * 16 + l16;
        float bv = bi[col];
        for (int i = 0; i < 4; i++) {
            int rbase = m0 + wm * 64 + i * 16 + quad * 4;
            for (int r = 0; r < 4; r++)
                gi[(size_t)(rbase + r) * TH + col] = acc[i][j][r] + bv;
        }
    }
}

// ---------------- pass 0: segment starts, h_prev == 0 (or last_state for t==0) ----------
// Also zeroes the wcnt dataflow counters (8192 ints, reusing the dead-after-gemm WiT
// region) — first 32 blocks, BEFORE the S0 gate, so it re-runs on every graph replay.
__global__ void pass0_kernel(const float* __restrict__ gi, const float* __restrict__ bhn,
                             const float* __restrict__ last_state, const float* __restrict__ Wh,
                             const int* __restrict__ term, const int* __restrict__ pos_list,
                             const int* __restrict__ meta, float* __restrict__ out,
                             unsigned short* __restrict__ hb, int* __restrict__ wcnt) {
    if (blockIdx.x < 32) wcnt[blockIdx.x * 256 + threadIdx.x] = 0;
    int S0 = meta[0];
    int b = blockIdx.x;
    if (b >= S0) return;
    int t = pos_list[meta[NB] + b];
    int tid = threadIdx.x;
    bool ls_path = (t == 0) && (term[0] == 0) && (meta[2 * NB] != 0);
    for (int u = 0; u < 4; u++) {
        int j = tid + u * 256;
        float gr = gi[(size_t)t * TH + j];
        float gz = gi[(size_t)t * TH + 1024 + j];
        float gn = gi[(size_t)t * TH + 2048 + j];
        float hp = 0.f, ghr = 0.f, ghz = 0.f, ghn = 0.f;
        if (ls_path) {  // general fallback (last_state != 0); not taken for this dataset
            hp = last_state[j];
            for (int k = 0; k < 1024; k++) {
                float hk = last_state[k];
                const float* w = Wh + (size_t)k * TH;
                ghr += hk * w[j]; ghz += hk * w[1024 + j]; ghn += hk * w[2048 + j];
            }
        }
        float r = sigm(gr + ghr);
        float z = sigm(gz + ghz);
        float n = tanh_fast(gn + r * (ghn + bhn[j]));
        float h = (1.f - z) * n + z * hp;
        out[(size_t)t * HD + j] = h;
        out[(size_t)(T_LEN + t) * HD + j] = h;
        hb[(size_t)t * HD + j] = f2bf(h);
    }
}

// ---------------- pass k in [1,4]: gathered-row GEMM h_prev @ Wh + fused gates --------
__global__ __launch_bounds__(256) void pass_gemm(const float* __restrict__ gi,
                                                 const float* __restrict__ bhn,
                                                 const unsigned short* __restrict__ WhT,
                                                 const unsigned short* __restrict__ hb,
                                                 float* __restrict__ out,
                                                 unsigned short* __restrict__ hbw,
                                                 const int* __restrict__ pos_list,
                                                 const int* __restrict__ meta, int k) {
    int S = meta[k];
    int off = meta[NB + k];
    int tid = threadIdx.x;
    int lane = tid & 63, wave = tid >> 6;
    int quad = lane >> 4, l16 = lane & 15;

    if (S <= SKINNY_MAX) {
        if (S == 0) return;
        int nrt = (S + 15) >> 4;
        int ntask = 64 * nrt;                       // 64 h-col tiles x row tiles
        int gwave = ((blockIdx.y * 16 + blockIdx.x) << 2) + wave;
        int nw = gridDim.x * gridDim.y * 4;
        for (int task = gwave; task < ntask; task += nw) {
            int ct = task & 63;
            int rt = task >> 6;
            int j = ct * 16 + l16;                  // h-col this lane owns
            int ra = rt * 16 + l16;
            ra = ra < S ? ra : S - 1;               // clamp: dup loads harmless
            int t_a = pos_list[off + ra];
            const unsigned short* ap = hb + (size_t)(t_a - 1) * HD + quad * 8;
            const unsigned short* bp = WhT + (size_t)j * 1024 + quad * 8;
            f32x4 acc[3] = {};
            #pragma unroll
            for (int ks = 0; ks < 32; ks++) {
                bf16x8 a  = *(const bf16x8*)(ap + ks * 32);
                bf16x8 b0 = *(const bf16x8*)(bp + ks * 32);
                bf16x8 b1 = *(const bf16x8*)(bp + 1048576 + ks * 32);   // gate z row block
                bf16x8 b2 = *(const bf16x8*)(bp + 2097152 + ks * 32);   // gate n row block
                acc[0] = __builtin_amdgcn_mfma_f32_16x16x32_bf16(a, b0, acc[0], 0, 0, 0);
                acc[1] = __builtin_amdgcn_mfma_f32_16x16x32_bf16(a, b1, acc[1], 0, 0, 0);
                acc[2] = __builtin_amdgcn_mfma_f32_16x16x32_bf16(a, b2, acc[2], 0, 0, 0);
            }
            // C layout: col = l16 (h-col j), row = quad*4 + r (row within 16-row tile)
            #pragma unroll
            for (int r = 0; r < 4; r++) {
                int rr = rt * 16 + quad * 4 + r;
                if (rr >= S) continue;
                int t = pos_list[off + rr];
                const float* girow = gi + (size_t)t * TH;
                float hp = out[(size_t)(t - 1) * HD + j];
                float rgt = sigm(girow[j] + acc[0][r]);
                float zgt = sigm(girow[1024 + j] + acc[1][r]);
                float ngt = tanh_fast(girow[2048 + j] + rgt * (acc[2][r] + bhn[j]));
                float hv = (1.f - zgt) * ngt + zgt * hp;
                out[(size_t)t * HD + j] = hv;
                out[(size_t)(T_LEN + t) * HD + j] = hv;
                hbw[(size_t)t * HD + j] = f2bf(hv);
            }
        }
        return;
    }

    // ---------------- LDS path (verified round-0 form) ----------------
    int r0 = blockIdx.y * 64;
    if (r0 >= S) return;
    int j0 = blockIdx.x * 64;
    __shared__ unsigned short As[4 * 64 * 32];    // 16 KB (four 32-K sub-tiles)
    __shared__ unsigned short Bs[4 * 192 * 32];   // 48 KB (row: gate g*64 + jj)
    int wm = wave & 1, wn = wave >> 1;

    // A gather: 256 chunks per sub-tile; chunk id = tid; row=tid>>2, sub=tid&3.
    int arow = tid >> 2, sub = tid & 3;
    bool av = (r0 + arow) < S;
    int t_a = av ? pos_list[off + r0 + arow] : 1;
    const unsigned short* hsrc = hb + (size_t)(t_a - 1) * HD + sub * 8;

    f32x4 acc[2][6] = {};
    for (int kb = 0; kb < 8; kb++) {
        int k0 = kb * 128;
        for (int ks = 0; ks < 4; ks++) {
            int kk0 = k0 + ks * 32;
            for (int p = 0; p < 3; p++) {      // B sub-tile: 768 chunks
                int c = tid + p * 256;
                int row = c >> 2, q = c & 3;
                int g = row >> 6, jj = row & 63;
                gld16(WhT + (size_t)(g * 1024 + j0 + jj) * 1024 + kk0 + q * 8,
                      Bs + ks * 6144 + c * 8);
            }
            // A sub-tile: 256 chunks (gathered rows; garbage rows >= S harmless)
            gld16(hsrc + kk0, As + ks * 2048 + tid * 8);
        }
        __syncthreads();
        for (int ks = 0; ks < 4; ks++) {
            bf16x8 af[2];
            for (int i = 0; i < 2; i++)
                af[i] = *(const bf16x8*)(As + ks * 2048 + (wm * 32 + i * 16 + l16) * 32 + quad * 8);
            for (int n = 0; n < 6; n++) {
                int g = n >> 1, jh = n & 1;
                bf16x8 bv = *(const bf16x8*)(Bs + ks * 6144 + (g * 64 + wn * 32 + jh * 16 + l16) * 32 + quad * 8);
                for (int i = 0; i < 2; i++)
                    acc[i][n] = __builtin_amdgcn_mfma_f32_16x16x32_bf16(af[i], bv, acc[i][n], 0, 0, 0);
            }
        }
        __syncthreads();
    }
    // epilogue: rows r0 + wm*32 + i*16 + quad*4 + r ; cols j0 + wn*32 + jh*16 + l16
    for (int i = 0; i < 2; i++) {
        for (int r = 0; r < 4; r++) {
            int rr = r0 + wm * 32 + i * 16 + quad * 4 + r;
            if (rr >= S) continue;
            int t = pos_list[off + rr];
            const float* girow = gi + (size_t)t * TH;
            const float* hprow = out + (size_t)(t - 1) * HD;
            float* o1 = out + (size_t)t * HD;
            float* o2 = out + (size_t)(T_LEN + t) * HD;
            unsigned short* hbrow = hbw + (size_t)t * HD;
            for (int jh = 0; jh < 2; jh++) {
                int j = j0 + wn * 32 + jh * 16 + l16;
                float ghr = acc[i][0 + jh][r];
                float ghz = acc[i][2 + jh][r];
                float ghn = acc[i][4 + jh][r];
                float rg = sigm(girow[j] + ghr);
                float zg = sigm(girow[1024 + j] + ghz);
                float ng = tanh_fast(girow[2048 + j] + rg * (ghn + bhn[j]));
                float h = (1.f - zg) * ng + zg * hprow[j];
                o1[j] = h;
                o2[j] = h;
                hbrow[j] = f2bf(h);
            }
        }
    }
}

// ---------------- merged skinny passes k=KSPLIT..14 — ONE launch, DATAFLOW sync ----
// r10 post-mortem: global device barrier = ~24us each (192us total, all idle) — WORSE
// than the ~11.6us/launch it replaced. This version has NO barriers: per-row ready
// counters. Producer: write row t's 16 cols -> __threadfence (wave-wide vmcnt drain +
// release; protocol proven correct in r10) -> atomicAdd(&wcnt[t],1). Each row gets 64
// increments (one per col-tile task). Consumer (level k>KSPLIT): spin with LOAD-ONLY
// device-scope polls (no RMW bouncing) until wcnt[t-1]==64, then acquire fence.
// Deadlock-free: waits only on strictly-lower levels; 512 waves (128 blk x 4) are all
// co-resident (<=1 blk/CU) so producers always make progress.
__global__ __launch_bounds__(256) void skinny_all(const float* __restrict__ gi,
                                                  const float* __restrict__ bhn,
                                                  const unsigned short* __restrict__ WhT,
                                                  unsigned short* __restrict__ hb,
                                                  float* __restrict__ out,
                                                  const int* __restrict__ pos_list,
                                                  const int* __restrict__ meta,
                                                  int* __restrict__ wcnt) {
    int tid = threadIdx.x;
    int lane = tid & 63, wave = tid >> 6;
    int quad = lane >> 4, l16 = lane & 15;
    int gwave = (blockIdx.x << 2) + wave;     // 0..511
    for (int k = KSPLIT; k <= NB - 2; k++) {
        int S = meta[k];
        if (S == 0) break;                    // uniform: later buckets (and tail) empty
        int off = meta[NB + k];
        int nrt = (S + 15) >> 4;
        int ntask = 64 * nrt;
        for (int task = gwave; task < ntask; task += 512) {
            int ct = task & 63;
            int rt = task >> 6;
            int j = ct * 16 + l16;
            int ra = rt * 16 + l16;
            ra = ra < S ? ra : S - 1;
            int t_a = pos_list[off + ra];
            if (k > KSPLIT) {                 // wait for level k-1 rows (in-kernel producers)
                for (;;) {
                    int c = __hip_atomic_load(&wcnt[t_a - 1], __ATOMIC_RELAXED,
                                              __HIP_MEMORY_SCOPE_AGENT);
                    if (__all(c >= 64)) break;
                    __builtin_amdgcn_s_sleep(1);
                }
                __threadfence();              // acquire: see producers' row data
            }
            const unsigned short* ap = hb + (size_t)(t_a - 1) * HD + quad * 8;
            const unsigned short* bp = WhT + (size_t)j * 1024 + quad * 8;
            f32x4 acc[3] = {};
            #pragma unroll
            for (int ks = 0; ks < 32; ks++) {
                bf16x8 a  = *(const bf16x8*)(ap + ks * 32);
                bf16x8 b0 = *(const bf16x8*)(bp + ks * 32);
                bf16x8 b1 = *(const bf16x8*)(bp + 1048576 + ks * 32);
                bf16x8 b2 = *(const bf16x8*)(bp + 2097152 + ks * 32);
                acc[0] = __builtin_amdgcn_mfma_f32_16x16x32_bf16(a, b0, acc[0], 0, 0, 0);
                acc[1] = __builtin_amdgcn_mfma_f32_16x16x32_bf16(a, b1, acc[1], 0, 0, 0);
                acc[2] = __builtin_amdgcn_mfma_f32_16x16x32_bf16(a, b2, acc[2], 0, 0, 0);
            }
            #pragma unroll
            for (int r = 0; r < 4; r++) {
                int rr = rt * 16 + quad * 4 + r;
                if (rr >= S) continue;
                int t = pos_list[off + rr];
                const float* girow = gi + (size_t)t * TH;
                float hp = out[(size_t)(t - 1) * HD + j];
                float rgt = sigm(girow[j] + acc[0][r]);
                float zgt = sigm(girow[1024 + j] + acc[1][r]);
                float ngt = tanh_fast(girow[2048 + j] + rgt * (acc[2][r] + bhn[j]));
                float hv = (1.f - zgt) * ngt + zgt * hp;
                out[(size_t)t * HD + j] = hv;
                out[(size_t)(T_LEN + t) * HD + j] = hv;
                hb[(size_t)t * HD + j] = f2bf(hv);
            }
            __threadfence();                  // release: row data visible before flags
            if (l16 == 0) {
                #pragma unroll
                for (int r = 0; r < 4; r++) {
                    int rr = rt * 16 + quad * 4 + r;
                    if (rr < S) atomicAdd(&wcnt[pos_list[off + rr]], 1);
                }
            }
        }
    }
}

// ---------------- tail: positions with local_step >= NB-1 (expected S==0) ----------
__global__ __launch_bounds__(256) void tail_pll(const float* __restrict__ gi,
                                                const float* __restrict__ bhn,
                                                const unsigned short* __restrict__ WhT,
                                                const int* __restrict__ pos_list,
                                                const int* __restrict__ meta,
                                                int* __restrict__ sync,
                                                float* __restrict__ out) {
    int S = meta[NB - 1];
    if (S == 0) return;
    __shared__ int pos[T_LEN];        // 32 KB: correctness path for any S
    __shared__ float hsh[HD];
    __shared__ float dots[192];
    int off = meta[NB + NB - 1];
    int tid = threadIdx.x;
    int j0 = blockIdx.x * 64;
    for (int i = tid; i < S; i += 256) pos[i] = pos_list[off + i];
    __syncthreads();
    if (tid == 0) {   // insertion sort by t (S expected tiny; redundant per block)
        for (int i = 1; i < S; i++) {
            int v = pos[i], j = i - 1;
            while (j >= 0 && pos[j] > v) { pos[j + 1] = pos[j]; j--; }
            pos[j + 1] = v;
        }
    }
    __syncthreads();
    for (int s = 0; s < S; s++) {
        int t = pos[s];
        for (int u = 0; u < 4; u++)    // stage h_prev (f32, from out)
            hsh[tid + u * 256] = out[(size_t)(t - 1) * HD + tid + u * 256];
        __syncthreads();
        if (tid < 192) {
            int g = tid >> 6, jj = tid & 63;
            int col = g * 1024 + j0 + jj;
            const unsigned short* wrow = WhT + (size_t)col * 1024;
            float acc = 0.f;
            for (int kk = 0; kk < 1024; kk += 8) {
                bf16x8 wv = *(const bf16x8*)(wrow + kk);
                f32x4 h0 = *(const f32x4*)(hsh + kk);
                f32x4 h1 = *(const f32x4*)(hsh + kk + 4);
                acc += h0[0] * bf2f((unsigned short)wv[0]) + h0[1] * bf2f((unsigned short)wv[1])
                     + h0[2] * bf2f((unsigned short)wv[2]) + h0[3] * bf2f((unsigned short)wv[3])
                     + h1[0] * bf2f((unsigned short)wv[4]) + h1[1] * bf2f((unsigned short)wv[5])
                     + h1[2] * bf2f((unsigned short)wv[6]) + h1[3] * bf2f((unsigned short)wv[7]);
            }
            dots[tid] = acc;
        }
        __syncthreads();
        if (tid < 64) {
            int j = j0 + tid;
            float rg = sigm(gi[(size_t)t * TH + j] + dots[tid]);
            float zg = sigm(gi[(size_t)t * TH + 1024 + j] + dots[64 + tid]);
            float ng = tanh_fast(gi[(size_t)t * TH + 2048 + j] + rg * (dots[128 + tid] + bhn[j]));
            float hv = (1.f - zg) * ng + zg * hsh[j];
            out[(size_t)t * HD + j] = hv;
            out[(size_t)(T_LEN + t) * HD + j] = hv;
        }
        // ---- manual device-scope inter-block barrier (16 blocks only) ----
        __threadfence();
        __syncthreads();
        if (tid == 0) {
            atomicAdd(sync, 1);
            int tgt = 16 * (s + 1);
            while (atomicAdd(sync, 0) < tgt)
                __builtin_amdgcn_s_sleep(8);
        }
        __syncthreads();
        __threadfence();
    }
}

extern "C" void kernel_launch(void* const* d_in, const int* in_sizes, int n_in,
                              void* d_out, int out_size, void* d_ws, size_t ws_size,
                              hipStream_t stream) {
    const float* X          = (const float*)d_in[0];
    const int*   term       = (const int*)d_in[1];
    const float* last_state = (const float*)d_in[2];
    const float* Wi         = (const float*)d_in[3];
    const float* bi         = (const float*)d_in[4];
    const float* Wh         = (const float*)d_in[5];
    const float* bhn        = (const float*)d_in[6];
    float* out = (float*)d_out;

    char* ws = (char*)d_ws;
    float*          gi       = (float*)ws;                         // 100,663,296 B
    unsigned short* Xb       = (unsigned short*)(ws + 100663296);  // 16,777,216 B (reused as hb)
    unsigned short* hb       = Xb;  // Xb dead after gemm_gi; stream order guarantees safety
    unsigned short* WiT      = (unsigned short*)(ws + 117440512);  //  6,291,456 B
    unsigned short* WhT      = (unsigned short*)(ws + 123731968);  //  6,291,456 B
    int*            pos_list = (int*)(ws + 130023424);             //     32,768 B
    int*            meta     = (int*)(ws + 130056192);             //        512 B
    int*            sync_t   = meta + 48;                          // tail barrier counter
    int*            wcnt     = (int*)WiT;  // 32 KB dataflow counters (WiT dead after gemm_gi)

    cast_x<<<dim3(8192), dim3(256), 0, stream>>>(X, Xb);
    transpose_cast<<<dim3(48, 16, 2), dim3(256), 0, stream>>>(Wi, Wh, WiT, WhT);
    meta_kernel<<<dim3(1), dim3(1024), 0, stream>>>(term, last_state, pos_list, meta);
    gemm_gi<<<dim3(24, 64), dim3(256), 0, stream>>>(Xb, WiT, bi, gi);
    pass0_kernel<<<dim3(8192), dim3(256), 0, stream>>>(gi, bhn, last_state, Wh, term, pos_list, meta, out, hb, wcnt);
    for (int k = 1; k < KSPLIT; k++) {
        int rows_max = T_LEN / (k + 1);     // S_k <= T/(k+1)
        int gy = (rows_max + 63) / 64;
        pass_gemm<<<dim3(16, gy), dim3(256), 0, stream>>>(gi, bhn, WhT, hb, out, hb, pos_list, meta, k);
    }
    skinny_all<<<dim3(128), dim3(256), 0, stream>>>(gi, bhn, WhT, hb, out, pos_list, meta, wcnt);
    tail_pll<<<dim3(16), dim3(256), 0, stream>>>(gi, bhn, WhT, pos_list, meta, sync_t, out);
}